// Round 2
// 712.235 us; speedup vs baseline: 1.0216x; 1.0216x over previous
//
#include <hip/hip_runtime.h>

// SVD_Layer: out = x @ W + b, W = einsum('ios,sIOS,Sab->iIaoOb', W1,W2,W3).reshape(768,3072)
// Sizes: x(32768,768) f32; W1(8,16,134); W2(134,12,12,134); W3(134,8,16); b(3072); out(32768,3072) f32.
// Strategy: build W in fp32 (2-step contraction), store as bf16 W^T (N-major,K-contig);
// cast x to bf16; run 256x256/BK32 MFMA GEMM with 4-deep LDS pipeline + counted vmcnt
// (catalog T1+T2+T3/T4+T5): XCD swizzle, XOR bank swizzle, global_load_lds(16B), setprio.
// R1 hardening: wave-uniform LDS base for global_load_lds (m104 spec), sched_barrier(0)
// after every raw s_barrier (rule #18/#19: barrier has no compiler memory semantics).

typedef unsigned short u16;
typedef unsigned int   u32;
typedef short s16x8 __attribute__((ext_vector_type(8)));   // 8 bf16 (4 VGPRs), guide §3
typedef float f32x4 __attribute__((ext_vector_type(4)));

__device__ __forceinline__ u16 f2bf(float f) {
  u32 u = __float_as_uint(f);
  u32 r = (u + 0x7FFFu + ((u >> 16) & 1u)) >> 16;   // RNE, finite inputs only
  return (u16)r;
}

__device__ __forceinline__ void gload_lds16(const void* g, void* l) {
  // async 16B/lane global->LDS; LDS dest must be wave-uniform base (+ lane*16 by HW)
  __builtin_amdgcn_global_load_lds(
      (const __attribute__((address_space(1))) void*)g,
      (__attribute__((address_space(3))) void*)l, 16, 0, 0);
}

// ---------------- kernel 1: x fp32 -> bf16 (8 elems/thread) ----------------
__global__ __launch_bounds__(256) void xconv_kernel(const float* __restrict__ x,
                                                    u16* __restrict__ xb) {
  size_t idx = ((size_t)blockIdx.x * 256 + threadIdx.x) * 8;
  float4 v0 = *(const float4*)(x + idx);
  float4 v1 = *(const float4*)(x + idx + 4);
  uint4 o;
  o.x = (u32)f2bf(v0.x) | ((u32)f2bf(v0.y) << 16);
  o.y = (u32)f2bf(v0.z) | ((u32)f2bf(v0.w) << 16);
  o.z = (u32)f2bf(v1.x) | ((u32)f2bf(v1.y) << 16);
  o.w = (u32)f2bf(v1.z) | ((u32)f2bf(v1.w) << 16);
  *(uint4*)(xb + idx) = o;
}

// ---------------- kernel 2: T1[io][I*1608+O*134+S] = sum_s W1[io*134+s]*W2[s*19296+ios] ----
__global__ __launch_bounds__(256) void a1_kernel(const float* __restrict__ W1,
                                                 const float* __restrict__ W2,
                                                 float* __restrict__ T1) {
  __shared__ float lW1[32 * 136];   // rows padded 134->136 for aligned float4 reads
  const int t = threadIdx.x;
  const int iog = blockIdx.y;               // io base = iog*32
  const int ios = blockIdx.x * 256 + t;     // 0..19455, valid < 19296
  for (int idx = t; idx < 32 * 136; idx += 256) {
    int u = idx / 136, s = idx - u * 136;
    lW1[idx] = (s < 134) ? W1[(size_t)(iog * 32 + u) * 134 + s] : 0.f;
  }
  __syncthreads();
  const bool valid = ios < 19296;
  float acc[32];
#pragma unroll
  for (int u = 0; u < 32; u++) acc[u] = 0.f;
  for (int s4 = 0; s4 < 136; s4 += 4) {
    float wa = (valid && s4 + 0 < 134) ? W2[(size_t)(s4 + 0) * 19296 + ios] : 0.f;
    float wb = (valid && s4 + 1 < 134) ? W2[(size_t)(s4 + 1) * 19296 + ios] : 0.f;
    float wc = (valid && s4 + 2 < 134) ? W2[(size_t)(s4 + 2) * 19296 + ios] : 0.f;
    float wd = (valid && s4 + 3 < 134) ? W2[(size_t)(s4 + 3) * 19296 + ios] : 0.f;
#pragma unroll
    for (int u = 0; u < 32; u++) {
      float4 wv = *(const float4*)&lW1[u * 136 + s4];   // broadcast read
      acc[u] += wv.x * wa + wv.y * wb + wv.z * wc + wv.w * wd;
    }
  }
  if (valid) {
#pragma unroll
    for (int u = 0; u < 32; u++)
      T1[(size_t)(iog * 32 + u) * 19296 + ios] = acc[u];
  }
}

// ---------------- kernel 3: Wt_bf16[col][k] = W[k][col], W = sum_S T1 * W3 ----------------
__global__ __launch_bounds__(128) void a2_kernel(const float* __restrict__ T1,
                                                 const float* __restrict__ W3,
                                                 u16* __restrict__ Wt) {
  __shared__ float lT[12 * 136];     // T1 slice [O][S], padded
  __shared__ u16 lOut[192 * 8];      // [O*16+b][a]
  const int t = threadIdx.x;         // 0..127 = a*16+b
  const int io = blockIdx.x;         // 0..127
  const int I = blockIdx.y;          // 0..11
  const int i = io >> 4, o = io & 15;
  const float* src = T1 + (size_t)io * 19296 + (size_t)I * 1608;
  for (int idx = t; idx < 12 * 136; idx += 128) {
    int O = idx / 136, S = idx - O * 136;
    lT[idx] = (S < 134) ? src[O * 134 + S] : 0.f;
  }
  __syncthreads();
  float acc[12];
#pragma unroll
  for (int O = 0; O < 12; O++) acc[O] = 0.f;
  for (int S4 = 0; S4 < 136; S4 += 4) {
    float w0 = (S4 + 0 < 134) ? W3[(S4 + 0) * 128 + t] : 0.f;
    float w1 = (S4 + 1 < 134) ? W3[(S4 + 1) * 128 + t] : 0.f;
    float w2 = (S4 + 2 < 134) ? W3[(S4 + 2) * 128 + t] : 0.f;
    float w3 = (S4 + 3 < 134) ? W3[(S4 + 3) * 128 + t] : 0.f;
#pragma unroll
    for (int O = 0; O < 12; O++) {
      float4 tv = *(const float4*)&lT[O * 136 + S4];   // broadcast read
      acc[O] += tv.x * w0 + tv.y * w1 + tv.z * w2 + tv.w * w3;
    }
  }
  const int a = t >> 4, b = t & 15;
#pragma unroll
  for (int O = 0; O < 12; O++) lOut[(O * 16 + b) * 8 + a] = f2bf(acc[O]);
  __syncthreads();
  for (int rr = t; rr < 192; rr += 128) {     // rr = O*16+b -> one Wt row, 8 contiguous k
    int col = o * 192 + rr;
    *(uint4*)&Wt[(size_t)col * 768 + i * 96 + I * 8] = *(const uint4*)&lOut[rr * 8];
  }
}

// ---------------- kernel 4: C = Xb(32768x768) * Wt^T + bias, bf16 MFMA ----------------
// 256x256 tile, BK=32, 8 waves (2Mx4N), each 128x64. 4 LDS buffers (128 KiB),
// prefetch distance 3 tiles, counted vmcnt (never 0 in steady state), XOR bank
// swizzle on both staging source and ds_read, setprio around MFMA clusters.

template <int N>
__device__ __forceinline__ void vmcnt_wait() {
  if constexpr (N == 12)     asm volatile("s_waitcnt vmcnt(12)" ::: "memory");
  else if constexpr (N == 8) asm volatile("s_waitcnt vmcnt(8)"  ::: "memory");
  else if constexpr (N == 4) asm volatile("s_waitcnt vmcnt(4)"  ::: "memory");
  else                       asm volatile("s_waitcnt vmcnt(0)"  ::: "memory");
}

__global__ __launch_bounds__(512, 2) void gemm_kernel(const u16* __restrict__ A,
                                                      const u16* __restrict__ Bt,
                                                      const float* __restrict__ bias,
                                                      float* __restrict__ C) {
  // 4 buffers x (A: 256x32 bf16 = 16KB, B: 256x32 bf16 = 16KB) = 128 KiB
  __shared__ u16 smem[4 * 16384];
  const int t = threadIdx.x;
  const int lane = t & 63, wid = t >> 6;
  const int wr = wid >> 2, wc = wid & 3;          // 2M x 4N wave grid
  const int q = lane >> 4, l16 = lane & 15;

  // XCD-aware bijective swizzle: nwg = 1536 = 8 * 192
  const int bid = blockIdx.x;
  const int swz = (bid & 7) * 192 + (bid >> 3);
  const int nIdx = swz % 12, mIdx = swz / 12;
  const int blockM = mIdx * 256, blockN = nIdx * 256;

  // ---- staging addressing (per thread, loop-invariant) ----
  // LDS linear byte L = chunk*8192 + t*16 -> row r = chunk*128 + (t>>2), stored kb = (t&3)*16.
  // Bank swizzle swz(r) = ((r>>1)&3)<<4; (r>>1)&3 == (t>>3)&3 for both chunks.
  // Pre-swizzled source: fetch logical kb_src = stored_kb ^ swz(r).
  const int kb_src = (((t & 3) ^ ((t >> 3) & 3)) << 4);        // bytes
  const int rA = t >> 2;                                        // 0..127 (+128 for chunk 1)
  const u16* gAs = A  + (size_t)(blockM + rA) * 768 + (kb_src >> 1);
  const u16* gBs = Bt + (size_t)(blockN + rA) * 768 + (kb_src >> 1);

  // wave-uniform LDS staging base: HW dest = base + lane*16B = smem[b*16384 + t*8] u16
#define STAGE(b_, kt_) do {                                     \
    const u16* ga_ = gAs + (kt_) * 32;                          \
    const u16* gb_ = gBs + (kt_) * 32;                          \
    u16* lw_ = &smem[(b_) * 16384 + wid * 512];                 \
    gload_lds16(ga_,             lw_);                          \
    gload_lds16(ga_ + 128 * 768, lw_ + 4096);                   \
    gload_lds16(gb_,             lw_ + 8192);                   \
    gload_lds16(gb_ + 128 * 768, lw_ + 12288);                  \
  } while (0)

  f32x4 acc[8][4];
  const f32x4 z = {0.f, 0.f, 0.f, 0.f};
#pragma unroll
  for (int mi = 0; mi < 8; mi++)
#pragma unroll
    for (int ni = 0; ni < 4; ni++) acc[mi][ni] = z;

  // read-side swizzled k-offset (u16 units): (q*8) ^ (((l16>>1)&3)*8)
  const int koff = (q << 3) ^ (((l16 >> 1) & 3) << 3);
  const int aRow = wr * 128 + l16;                 // + mi*16
  const int bRow = wc * 64 + l16;                  // + ni*16

#define COMPUTE(bb_) do {                                                       \
    const u16* lA_ = &smem[(bb_) * 16384];                                      \
    const u16* lB_ = lA_ + 8192;                                                \
    s16x8 bg[4], af[4], af2[4];                                                 \
    _Pragma("unroll")                                                           \
    for (int ni = 0; ni < 4; ni++)                                              \
      bg[ni] = *(const s16x8*)&lB_[(bRow + ni * 16) * 32 + koff];               \
    _Pragma("unroll")                                                           \
    for (int mi = 0; mi < 4; mi++)                                              \
      af[mi] = *(const s16x8*)&lA_[(aRow + mi * 16) * 32 + koff];               \
    _Pragma("unroll")                                                           \
    for (int mi = 0; mi < 4; mi++)                                              \
      af2[mi] = *(const s16x8*)&lA_[(aRow + (mi + 4) * 16) * 32 + koff];        \
    __builtin_amdgcn_s_setprio(1);                                              \
    _Pragma("unroll")                                                           \
    for (int mi = 0; mi < 4; mi++)                                              \
      _Pragma("unroll")                                                         \
      for (int ni = 0; ni < 4; ni++)                                            \
        acc[mi][ni] = __builtin_amdgcn_mfma_f32_16x16x32_bf16(af[mi], bg[ni],   \
                                                              acc[mi][ni], 0, 0, 0); \
    __builtin_amdgcn_s_setprio(0);                                              \
    __builtin_amdgcn_s_setprio(1);                                              \
    _Pragma("unroll")                                                           \
    for (int mi = 0; mi < 4; mi++)                                              \
      _Pragma("unroll")                                                         \
      for (int ni = 0; ni < 4; ni++)                                            \
        acc[mi + 4][ni] = __builtin_amdgcn_mfma_f32_16x16x32_bf16(af2[mi], bg[ni], \
                                                              acc[mi + 4][ni], 0, 0, 0); \
    __builtin_amdgcn_s_setprio(0);                                              \
  } while (0)

  // prologue: fill pipeline 3 deep (12 outstanding loads per wave)
  STAGE(0, 0);
  STAGE(1, 1);
  STAGE(2, 2);

  // steady state: tiles 0..20, stage tile tt+3 into buf (tt+3)&3 (== (tt-1)&3,
  // fully read in tile tt-1, protected by trailing barrier). vmcnt(12) gates
  // tile tt's 4 loads; barrier makes all waves' slices visible; sched_barrier(0)
  // pins ds_reads/stages on the correct side of each barrier (rule #18/#19).
  for (int tt = 0; tt < 21; ++tt) {
    STAGE((tt + 3) & 3, tt + 3);
    vmcnt_wait<12>();
    __builtin_amdgcn_s_barrier();
    __builtin_amdgcn_sched_barrier(0);
    COMPUTE(tt & 3);
    __builtin_amdgcn_sched_barrier(0);
    __builtin_amdgcn_s_barrier();
    __builtin_amdgcn_sched_barrier(0);
  }
  // tail: tiles 21,22,23 — no staging, drain 8/4/0
  vmcnt_wait<8>();
  __builtin_amdgcn_s_barrier();
  __builtin_amdgcn_sched_barrier(0);
  COMPUTE(1);
  __builtin_amdgcn_sched_barrier(0);
  __builtin_amdgcn_s_barrier();
  vmcnt_wait<4>();
  __builtin_amdgcn_s_barrier();
  __builtin_amdgcn_sched_barrier(0);
  COMPUTE(2);
  __builtin_amdgcn_sched_barrier(0);
  __builtin_amdgcn_s_barrier();
  vmcnt_wait<0>();
  __builtin_amdgcn_s_barrier();
  __builtin_amdgcn_sched_barrier(0);
  COMPUTE(3);

  // epilogue: C/D layout col=lane&15, row=(lane>>4)*4+reg (verified mapping, m89/m91)
  const int colBase = blockN + wc * 64 + l16;
#pragma unroll
  for (int ni = 0; ni < 4; ni++) {
    const int col = colBase + ni * 16;
    const float bv = bias[col];
#pragma unroll
    for (int mi = 0; mi < 8; mi++) {
      const int row = blockM + wr * 128 + mi * 16 + q * 4;
      float* cp = C + (size_t)row * 3072 + col;
      cp[0]        = acc[mi][ni][0] + bv;
      cp[3072]     = acc[mi][ni][1] + bv;
      cp[2 * 3072] = acc[mi][ni][2] + bv;
      cp[3 * 3072] = acc[mi][ni][3] + bv;
    }
  }
#undef STAGE
#undef COMPUTE
}

extern "C" void kernel_launch(void* const* d_in, const int* in_sizes, int n_in,
                              void* d_out, int out_size, void* d_ws, size_t ws_size,
                              hipStream_t stream) {
  const float* x  = (const float*)d_in[0];   // 32768*768
  const float* W1 = (const float*)d_in[1];   // 8*16*134
  const float* W2 = (const float*)d_in[2];   // 134*12*12*134
  const float* W3 = (const float*)d_in[3];   // 134*8*16
  const float* b  = (const float*)d_in[4];   // 3072
  float* out = (float*)d_out;

  char* ws = (char*)d_ws;
  u16* Xb   = (u16*)ws;                              // 50,331,648 B
  u16* Wt   = (u16*)(ws + 50331648);                 //  4,718,592 B
  float* T1 = (float*)(ws + 50331648 + 4718592);     //  9,879,552 B (total ~62 MB)

  xconv_kernel<<<12288, 256, 0, stream>>>(x, Xb);
  a1_kernel<<<dim3(76, 4), 256, 0, stream>>>(W1, W2, T1);
  a2_kernel<<<dim3(128, 12), 128, 0, stream>>>(T1, W3, Wt);
  gemm_kernel<<<dim3(1536), 512, 0, stream>>>(Xb, Wt, b, out);
}

// Round 3
// 704.369 us; speedup vs baseline: 1.0330x; 1.0112x over previous
//
#include <hip/hip_runtime.h>

// SVD_Layer: out = x @ W + b, W = einsum('ios,sIOS,Sab->iIaoOb', W1,W2,W3).reshape(768,3072)
// Sizes: x(32768,768) f32; W1(8,16,134); W2(134,12,12,134); W3(134,8,16); b(3072); out(32768,3072) f32.
// Strategy: build W in fp32 (2-step contraction), store as bf16 W^T (N-major,K-contig);
// cast x to bf16; 256x256/BK32 MFMA GEMM, 4-buffer LDS ring (3-tile lookahead),
// R3: fine 2-phase-per-tile interleave (m201 template shape: reads+stage | bar |
// lgkmcnt(0) | setprio MFMA | bar), counted vmcnt(8) after compute, NO sched_barrier.

typedef unsigned short u16;
typedef unsigned int   u32;
typedef short s16x8 __attribute__((ext_vector_type(8)));   // 8 bf16 (4 VGPRs), guide §3
typedef float f32x4 __attribute__((ext_vector_type(4)));

__device__ __forceinline__ u16 f2bf(float f) {
  u32 u = __float_as_uint(f);
  u32 r = (u + 0x7FFFu + ((u >> 16) & 1u)) >> 16;   // RNE, finite inputs only
  return (u16)r;
}

__device__ __forceinline__ void gload_lds16(const void* g, void* l) {
  // async 16B/lane global->LDS; LDS dest must be wave-uniform base (+ lane*16 by HW)
  __builtin_amdgcn_global_load_lds(
      (const __attribute__((address_space(1))) void*)g,
      (__attribute__((address_space(3))) void*)l, 16, 0, 0);
}

// ---------------- kernel 1: x fp32 -> bf16 (8 elems/thread) ----------------
__global__ __launch_bounds__(256) void xconv_kernel(const float* __restrict__ x,
                                                    u16* __restrict__ xb) {
  size_t idx = ((size_t)blockIdx.x * 256 + threadIdx.x) * 8;
  float4 v0 = *(const float4*)(x + idx);
  float4 v1 = *(const float4*)(x + idx + 4);
  uint4 o;
  o.x = (u32)f2bf(v0.x) | ((u32)f2bf(v0.y) << 16);
  o.y = (u32)f2bf(v0.z) | ((u32)f2bf(v0.w) << 16);
  o.z = (u32)f2bf(v1.x) | ((u32)f2bf(v1.y) << 16);
  o.w = (u32)f2bf(v1.z) | ((u32)f2bf(v1.w) << 16);
  *(uint4*)(xb + idx) = o;
}

// ---------------- kernel 2: T1[io][I*1608+O*134+S] = sum_s W1[io*134+s]*W2[s*19296+ios] ----
__global__ __launch_bounds__(256) void a1_kernel(const float* __restrict__ W1,
                                                 const float* __restrict__ W2,
                                                 float* __restrict__ T1) {
  __shared__ float lW1[32 * 136];   // rows padded 134->136 for aligned float4 reads
  const int t = threadIdx.x;
  const int iog = blockIdx.y;               // io base = iog*32
  const int ios = blockIdx.x * 256 + t;     // 0..19455, valid < 19296
  for (int idx = t; idx < 32 * 136; idx += 256) {
    int u = idx / 136, s = idx - u * 136;
    lW1[idx] = (s < 134) ? W1[(size_t)(iog * 32 + u) * 134 + s] : 0.f;
  }
  __syncthreads();
  const bool valid = ios < 19296;
  float acc[32];
#pragma unroll
  for (int u = 0; u < 32; u++) acc[u] = 0.f;
  for (int s4 = 0; s4 < 136; s4 += 4) {
    float wa = (valid && s4 + 0 < 134) ? W2[(size_t)(s4 + 0) * 19296 + ios] : 0.f;
    float wb = (valid && s4 + 1 < 134) ? W2[(size_t)(s4 + 1) * 19296 + ios] : 0.f;
    float wc = (valid && s4 + 2 < 134) ? W2[(size_t)(s4 + 2) * 19296 + ios] : 0.f;
    float wd = (valid && s4 + 3 < 134) ? W2[(size_t)(s4 + 3) * 19296 + ios] : 0.f;
#pragma unroll
    for (int u = 0; u < 32; u++) {
      float4 wv = *(const float4*)&lW1[u * 136 + s4];   // broadcast read
      acc[u] += wv.x * wa + wv.y * wb + wv.z * wc + wv.w * wd;
    }
  }
  if (valid) {
#pragma unroll
    for (int u = 0; u < 32; u++)
      T1[(size_t)(iog * 32 + u) * 19296 + ios] = acc[u];
  }
}

// ---------------- kernel 3: Wt_bf16[col][k] = W[k][col], W = sum_S T1 * W3 ----------------
__global__ __launch_bounds__(128) void a2_kernel(const float* __restrict__ T1,
                                                 const float* __restrict__ W3,
                                                 u16* __restrict__ Wt) {
  __shared__ float lT[12 * 136];     // T1 slice [O][S], padded
  __shared__ u16 lOut[192 * 8];      // [O*16+b][a]
  const int t = threadIdx.x;         // 0..127 = a*16+b
  const int io = blockIdx.x;         // 0..127
  const int I = blockIdx.y;          // 0..11
  const int i = io >> 4, o = io & 15;
  const float* src = T1 + (size_t)io * 19296 + (size_t)I * 1608;
  for (int idx = t; idx < 12 * 136; idx += 128) {
    int O = idx / 136, S = idx - O * 136;
    lT[idx] = (S < 134) ? src[O * 134 + S] : 0.f;
  }
  __syncthreads();
  float acc[12];
#pragma unroll
  for (int O = 0; O < 12; O++) acc[O] = 0.f;
  for (int S4 = 0; S4 < 136; S4 += 4) {
    float w0 = (S4 + 0 < 134) ? W3[(S4 + 0) * 128 + t] : 0.f;
    float w1 = (S4 + 1 < 134) ? W3[(S4 + 1) * 128 + t] : 0.f;
    float w2 = (S4 + 2 < 134) ? W3[(S4 + 2) * 128 + t] : 0.f;
    float w3 = (S4 + 3 < 134) ? W3[(S4 + 3) * 128 + t] : 0.f;
#pragma unroll
    for (int O = 0; O < 12; O++) {
      float4 tv = *(const float4*)&lT[O * 136 + S4];   // broadcast read
      acc[O] += tv.x * w0 + tv.y * w1 + tv.z * w2 + tv.w * w3;
    }
  }
  const int a = t >> 4, b = t & 15;
#pragma unroll
  for (int O = 0; O < 12; O++) lOut[(O * 16 + b) * 8 + a] = f2bf(acc[O]);
  __syncthreads();
  for (int rr = t; rr < 192; rr += 128) {     // rr = O*16+b -> one Wt row, 8 contiguous k
    int col = o * 192 + rr;
    *(uint4*)&Wt[(size_t)col * 768 + i * 96 + I * 8] = *(const uint4*)&lOut[rr * 8];
  }
}

// ---------------- kernel 4: C = Xb(32768x768) * Wt^T + bias, bf16 MFMA ----------------
// 256x256 tile, BK=32, 8 waves (2Mx4N), each 128x64. 4 LDS buffers (128 KiB),
// 3-tile lookahead, counted vmcnt(8) once per tile (after compute, never 0 in
// steady state), fine 2-phase interleave per tile, setprio around MFMA clusters,
// XOR bank swizzle on both staging source and ds_read.

template <int N>
__device__ __forceinline__ void vmcnt_wait() {
  if constexpr (N == 8)      asm volatile("s_waitcnt vmcnt(8)"  ::: "memory");
  else if constexpr (N == 4) asm volatile("s_waitcnt vmcnt(4)"  ::: "memory");
  else if constexpr (N == 0) asm volatile("s_waitcnt vmcnt(0)"  ::: "memory");
  // N == -1: no gate
}

#define LGKMCNT0() asm volatile("s_waitcnt lgkmcnt(0)" ::: "memory")

__global__ __launch_bounds__(512, 2) void gemm_kernel(const u16* __restrict__ A,
                                                      const u16* __restrict__ Bt,
                                                      const float* __restrict__ bias,
                                                      float* __restrict__ C) {
  // 4 buffers x (A: 256x32 bf16 = 16KB, B: 256x32 bf16 = 16KB) = 128 KiB
  __shared__ u16 smem[4 * 16384];
  const int t = threadIdx.x;
  const int lane = t & 63, wid = t >> 6;
  const int wr = wid >> 2, wc = wid & 3;          // 2M x 4N wave grid
  const int q = lane >> 4, l16 = lane & 15;

  // XCD-aware bijective swizzle: nwg = 1536 = 8 * 192
  const int bid = blockIdx.x;
  const int swz = (bid & 7) * 192 + (bid >> 3);
  const int nIdx = swz % 12, mIdx = swz / 12;
  const int blockM = mIdx * 256, blockN = nIdx * 256;

  // ---- staging addressing (per thread, loop-invariant) ----
  // LDS linear byte L = chunk*8192 + t*16 -> row r = chunk*128 + (t>>2), stored kb = (t&3)*16.
  // Bank swizzle swz(r) = ((r>>1)&3)<<4; (r>>1)&3 == (t>>3)&3 for both chunks.
  // Pre-swizzled source: fetch logical kb_src = stored_kb ^ swz(r).
  const int kb_src = (((t & 3) ^ ((t >> 3) & 3)) << 4);        // bytes
  const int rA = t >> 2;                                        // 0..127 (+128 for chunk 1)
  const u16* gAs = A  + (size_t)(blockM + rA) * 768 + (kb_src >> 1);
  const u16* gBs = Bt + (size_t)(blockN + rA) * 768 + (kb_src >> 1);

  f32x4 acc[8][4];
  const f32x4 z = {0.f, 0.f, 0.f, 0.f};
#pragma unroll
  for (int mi = 0; mi < 8; mi++)
#pragma unroll
    for (int ni = 0; ni < 4; ni++) acc[mi][ni] = z;

  // read-side swizzled k-offset (u16 units): (q*8) ^ (((l16>>1)&3)*8)
  const int koff = (q << 3) ^ (((l16 >> 1) & 3) << 3);
  const int aRow = wr * 128 + l16;                 // + mi*16
  const int bRow = wc * 64 + l16;                  // + ni*16

  // One K-tile = two template-shaped phases:
  //  ph1: {bg[0..3]+af[0..3] ds_reads | stage A of tile kt+3 | bar | lgkmcnt(0) |
  //        setprio(1) 16 MFMA (mi 0-3) setprio(0) | bar}
  //  ph2: {af2 ds_reads | stage B of tile kt+3 | bar | lgkmcnt(0) |
  //        setprio(1) 16 MFMA (mi 4-7) setprio(0) | vmcnt(GATE) | bar}
  // Issue order per tile: A-pair then B-pair (FIFO); outstanding at gate =
  // tiles kt+1,kt+2,kt+3 = 12 loads -> vmcnt(8) completes tile kt+1.
#define TILE_BODY(kt_, STG_, GATE_) do {                                        \
    const u16* lA_ = &smem[((kt_) & 3) * 16384];                                \
    const u16* lB_ = lA_ + 8192;                                                \
    s16x8 bg[4], af[4], af2[4];                                                 \
    _Pragma("unroll")                                                           \
    for (int ni = 0; ni < 4; ni++)                                              \
      bg[ni] = *(const s16x8*)&lB_[(bRow + ni * 16) * 32 + koff];               \
    _Pragma("unroll")                                                           \
    for (int mi = 0; mi < 4; mi++)                                              \
      af[mi] = *(const s16x8*)&lA_[(aRow + mi * 16) * 32 + koff];               \
    if (STG_) {                                                                 \
      u16* lw_ = &smem[(((kt_) + 3) & 3) * 16384 + wid * 512];                  \
      const u16* ga_ = gAs + ((kt_) + 3) * 32;                                  \
      gload_lds16(ga_,             lw_);                                        \
      gload_lds16(ga_ + 128 * 768, lw_ + 4096);                                 \
    }                                                                           \
    __builtin_amdgcn_s_barrier();                                               \
    LGKMCNT0();                                                                 \
    __builtin_amdgcn_s_setprio(1);                                              \
    _Pragma("unroll")                                                           \
    for (int mi = 0; mi < 4; mi++)                                              \
      _Pragma("unroll")                                                         \
      for (int ni = 0; ni < 4; ni++)                                            \
        acc[mi][ni] = __builtin_amdgcn_mfma_f32_16x16x32_bf16(af[mi], bg[ni],   \
                                                              acc[mi][ni], 0, 0, 0); \
    __builtin_amdgcn_s_setprio(0);                                              \
    __builtin_amdgcn_s_barrier();                                               \
    _Pragma("unroll")                                                           \
    for (int mi = 0; mi < 4; mi++)                                              \
      af2[mi] = *(const s16x8*)&lA_[(aRow + (mi + 4) * 16) * 32 + koff];        \
    if (STG_) {                                                                 \
      u16* lw_ = &smem[(((kt_) + 3) & 3) * 16384 + wid * 512];                  \
      const u16* gb_ = gBs + ((kt_) + 3) * 32;                                  \
      gload_lds16(gb_,             lw_ + 8192);                                 \
      gload_lds16(gb_ + 128 * 768, lw_ + 12288);                                \
    }                                                                           \
    __builtin_amdgcn_s_barrier();                                               \
    LGKMCNT0();                                                                 \
    __builtin_amdgcn_s_setprio(1);                                              \
    _Pragma("unroll")                                                           \
    for (int mi = 0; mi < 4; mi++)                                              \
      _Pragma("unroll")                                                         \
      for (int ni = 0; ni < 4; ni++)                                            \
        acc[mi + 4][ni] = __builtin_amdgcn_mfma_f32_16x16x32_bf16(af2[mi], bg[ni], \
                                                              acc[mi + 4][ni], 0, 0, 0); \
    __builtin_amdgcn_s_setprio(0);                                              \
    vmcnt_wait<GATE_>();                                                        \
    __builtin_amdgcn_s_barrier();                                               \
  } while (0)

  // prologue: stage tiles 0,1,2 (12 loads, FIFO: t0 A,B, t1 A,B, t2 A,B);
  // vmcnt(8) -> tile 0 resident; barrier publishes all waves' slices.
#pragma unroll
  for (int pk = 0; pk < 3; ++pk) {
    u16* lw_ = &smem[pk * 16384 + wid * 512];
    const u16* ga_ = gAs + pk * 32;
    const u16* gb_ = gBs + pk * 32;
    gload_lds16(ga_,             lw_);
    gload_lds16(ga_ + 128 * 768, lw_ + 4096);
    gload_lds16(gb_,             lw_ + 8192);
    gload_lds16(gb_ + 128 * 768, lw_ + 12288);
  }
  vmcnt_wait<8>();
  __builtin_amdgcn_s_barrier();

#pragma unroll 1
  for (int kt = 0; kt < 21; ++kt) {
    TILE_BODY(kt, 1, 8);
  }
  // tail: tiles 21,22,23 — no staging; gates drain 4 -> 0 -> none
  TILE_BODY(21, 0, 4);
  TILE_BODY(22, 0, 0);
  TILE_BODY(23, 0, -1);
#undef TILE_BODY

  // epilogue: C/D layout col=lane&15, row=(lane>>4)*4+reg (verified mapping, m89/m91)
  const int colBase = blockN + wc * 64 + l16;
#pragma unroll
  for (int ni = 0; ni < 4; ni++) {
    const int col = colBase + ni * 16;
    const float bv = bias[col];
#pragma unroll
    for (int mi = 0; mi < 8; mi++) {
      const int row = blockM + wr * 128 + mi * 16 + q * 4;
      float* cp = C + (size_t)row * 3072 + col;
      cp[0]        = acc[mi][ni][0] + bv;
      cp[3072]     = acc[mi][ni][1] + bv;
      cp[2 * 3072] = acc[mi][ni][2] + bv;
      cp[3 * 3072] = acc[mi][ni][3] + bv;
    }
  }
}

extern "C" void kernel_launch(void* const* d_in, const int* in_sizes, int n_in,
                              void* d_out, int out_size, void* d_ws, size_t ws_size,
                              hipStream_t stream) {
  const float* x  = (const float*)d_in[0];   // 32768*768
  const float* W1 = (const float*)d_in[1];   // 8*16*134
  const float* W2 = (const float*)d_in[2];   // 134*12*12*134
  const float* W3 = (const float*)d_in[3];   // 134*8*16
  const float* b  = (const float*)d_in[4];   // 3072
  float* out = (float*)d_out;

  char* ws = (char*)d_ws;
  u16* Xb   = (u16*)ws;                              // 50,331,648 B
  u16* Wt   = (u16*)(ws + 50331648);                 //  4,718,592 B
  float* T1 = (float*)(ws + 50331648 + 4718592);     //  9,879,552 B (total ~62 MB)

  xconv_kernel<<<12288, 256, 0, stream>>>(x, Xb);
  a1_kernel<<<dim3(76, 4), 256, 0, stream>>>(W1, W2, T1);
  a2_kernel<<<dim3(128, 12), 128, 0, stream>>>(T1, W3, Wt);
  gemm_kernel<<<dim3(1536), 512, 0, stream>>>(Xb, Wt, b, out);
}